// Round 10
// baseline (1616.714 us; speedup 1.0000x reference)
//
#include <hip/hip_runtime.h>
#include <math.h>

// Problem constants
#define D_IN    512
#define HID     1024
#define CHUNK_L 256
#define NCHUNK  16
#define SEQ_L   4096
#define ROWS    1024      // 4 batches x 256 chunk rows
#define NROWS_T 16384     // total rows (4 x 4096)
#define NB_LOOP 256

typedef __attribute__((ext_vector_type(4))) float f32x4;
typedef __attribute__((ext_vector_type(8))) short bf16x8;
typedef __attribute__((ext_vector_type(4))) short bf16x4;

#define LOSS_SCALE (2.0f / 524288.0f)

__device__ __forceinline__ float gelu_f(float v) {
    return v * 0.5f * (1.0f + erff(v * 0.70710678118654752f));
}
__device__ __forceinline__ float dgelu_f(float v) {
    float cdf = 0.5f * (1.0f + erff(v * 0.70710678118654752f));
    float pdf = 0.3989422804014327f * expf(-0.5f * v * v);
    return cdf + v * pdf;
}
__device__ __forceinline__ float sigmoid_dev(float x) { return 1.0f / (1.0f + expf(-x)); }
__device__ __forceinline__ short f2b(float f) {
    unsigned u = __float_as_uint(f);
    u += 0x7fffu + ((u >> 16) & 1u);
    return (short)(u >> 16);
}
__device__ __forceinline__ float b2f(short s) {
    return __uint_as_float(((unsigned)(unsigned short)s) << 16);
}
// fp32 proven (R3); plausibility hedge kept for the 3 logits (|v| in [2.2,7])
__device__ __forceinline__ float read_scalar(const float* p) {
    float v = *p;
    if (fabsf(v) > 0.5f && fabsf(v) < 16.0f) return v;
    unsigned short lo = ((const unsigned short*)p)[0];
    return __uint_as_float(((unsigned)lo) << 16);
}

// global_load_lds width=16: wave-uniform LDS base + lane*16B dest; per-lane
// global source address (m104/m173).
__device__ __forceinline__ void glds16(const short* g, short* l) {
    __builtin_amdgcn_global_load_lds(
        (const __attribute__((address_space(1))) void*)g,
        (__attribute__((address_space(3))) void*)l, 16, 0, 0);
}

// ---------------------------------------------------------------------------
// GEMM core (R5-R8-proven): C_tile = A[m][k] @ B[n][k]^T, 64x64 tile, BK=64,
// 4 waves. global_load_lds staging into NSLOT rolling LDS window (16 KB/slot),
// counted vmcnt pipeline depth NSLOT-1, one s_barrier per k-block, XOR
// granule swizzle both sides (rule #21).
// ---------------------------------------------------------------------------
#define VMWAIT(N) asm volatile("s_waitcnt vmcnt(" #N ")" ::: "memory")

template<int NKB, int NSLOT>
__device__ __forceinline__ void tile_gemm2(
    const short* __restrict__ A, int lda,
    const short* __restrict__ B, int ldb,
    int m0, int n0, short* KB, f32x4 acc[2][2])
{
    const int tid = threadIdx.x;
    const int lane = tid & 63, wave = tid >> 6;
    const int wy = (wave >> 1) * 32, wx = (wave & 1) * 32;
    const int l16 = lane & 15, q = lane >> 4;

    // per-lane source granules (granule g: row=g>>3, col-slot j=g&7)
    const int ga = tid, gb = tid + 256;
    const int ra = ga >> 3, ja = ga & 7;
    const int rb = gb >> 3, jb = gb & 7;
    const short* sA0 = A + (size_t)(m0 + ra) * lda + ((ja ^ (ra & 7)) << 3);
    const short* sA1 = A + (size_t)(m0 + rb) * lda + ((jb ^ (rb & 7)) << 3);
    const short* sB0 = B + (size_t)(n0 + ra) * ldb + ((ja ^ (ra & 7)) << 3);
    const short* sB1 = B + (size_t)(n0 + rb) * ldb + ((jb ^ (rb & 7)) << 3);

    f32x4 z = {0.f, 0.f, 0.f, 0.f};
    acc[0][0] = z; acc[0][1] = z; acc[1][0] = z; acc[1][1] = z;

    auto issue = [&](int kb) {
        const int ko = kb << 6;                      // shorts along K
        short* d = KB + (kb % NSLOT) * 8192 + wave * 512;
        glds16(sA0 + ko, d);
        glds16(sA1 + ko, d + 2048);
        glds16(sB0 + ko, d + 4096);
        glds16(sB1 + ko, d + 6144);
    };
#pragma unroll
    for (int kb = 0; kb < NSLOT - 1 && kb < NKB; ++kb) issue(kb);

#pragma unroll
    for (int j = 0; j < NKB; ++j) {
        // allowed outstanding k-blocks ahead of j (compile-time after unroll)
        int ah = NKB - 1 - j; if (ah > NSLOT - 2) ah = NSLOT - 2;
        if      (ah >= 6) VMWAIT(24);
        else if (ah == 5) VMWAIT(20);
        else if (ah == 4) VMWAIT(16);
        else if (ah == 3) VMWAIT(12);
        else if (ah == 2) VMWAIT(8);
        else if (ah == 1) VMWAIT(4);
        else              VMWAIT(0);
        __builtin_amdgcn_s_barrier();
        __builtin_amdgcn_sched_barrier(0);
        if (j + NSLOT - 1 < NKB) issue(j + NSLOT - 1);
        const short* sl = KB + (j % NSLOT) * 8192;
#pragma unroll
        for (int ks = 0; ks < 2; ++ks) {
            bf16x8 af[2], bf[2];
#pragma unroll
            for (int i = 0; i < 2; ++i) {
                int row = wy + i * 16 + l16;
                af[i] = *(const bf16x8*)&sl[(row << 6) + (((ks * 4 + q) ^ (row & 7)) << 3)];
            }
#pragma unroll
            for (int jj = 0; jj < 2; ++jj) {
                int row = wx + jj * 16 + l16;
                bf[jj] = *(const bf16x8*)&sl[4096 + (row << 6) + (((ks * 4 + q) ^ (row & 7)) << 3)];
            }
#pragma unroll
            for (int i = 0; i < 2; ++i)
#pragma unroll
                for (int jj = 0; jj < 2; ++jj)
                    acc[i][jj] = __builtin_amdgcn_mfma_f32_16x16x32_bf16(af[i], bf[jj], acc[i][jj], 0, 0, 0);
        }
    }
}

// epilogue index helper (m89 C/D layout: col=lane&15, row=(lane>>4)*4+reg)
#define EPI_IDX() \
    const int tid_ = threadIdx.x; \
    const int wy_  = ((tid_ >> 6) >> 1) * 32; \
    const int wxl_ = ((tid_ >> 6) & 1) * 32; \
    const int q4_  = ((tid_ & 63) >> 4) * 4; \
    const int l16_ = tid_ & 15;

// ---------------------------------------------------------------------------
// Grid barrier v3 (R17). R4's version used fetch_add on ONE address: 256
// device-scope RMWs serialize at the coherence point (~15-25us/barrier,
// matching R4's +17.6us/phase excess). v3: per-block flag STORES (distinct
// words, parallel), block 0's 256 threads poll the array in parallel and
// release one 'go' word; everyone spins on 'go' with RELAXED reads (read
// sharing doesn't serialize) + ONE acquire at exit. Protocol shape = R4's
// (correctness-proven); hotspot removed.
// ---------------------------------------------------------------------------
__device__ __forceinline__ void gsync(unsigned* flags, unsigned* go, unsigned gen)
{
    __syncthreads();
    if (threadIdx.x == 0)
        __hip_atomic_store(&flags[blockIdx.x], gen, __ATOMIC_RELEASE, __HIP_MEMORY_SCOPE_AGENT);
    if (blockIdx.x == 0) {
        unsigned v;
        do {
            __builtin_amdgcn_s_sleep(1);
            v = __hip_atomic_load(&flags[threadIdx.x], __ATOMIC_RELAXED, __HIP_MEMORY_SCOPE_AGENT);
        } while (v < gen);
        __syncthreads();
        if (threadIdx.x == 0)
            __hip_atomic_store(go, gen, __ATOMIC_RELEASE, __HIP_MEMORY_SCOPE_AGENT);
    }
    if (threadIdx.x == 0) {
        while (__hip_atomic_load(go, __ATOMIC_RELAXED, __HIP_MEMORY_SCOPE_AGENT) < gen)
            __builtin_amdgcn_s_sleep(2);
        (void)__hip_atomic_load(go, __ATOMIC_ACQUIRE, __HIP_MEMORY_SCOPE_AGENT);
    }
    __syncthreads();
}

// ---------------------------------------------------------------------------
// init: fp32 masters + bf16 operand copies + barrier reset
// ---------------------------------------------------------------------------
__global__ __launch_bounds__(256)
void init_all(const float* __restrict__ w_q, const float* __restrict__ w_k,
              const float* __restrict__ w_v, const float* __restrict__ m1,
              const float* __restrict__ m2,
              float* __restrict__ W1f, float* __restrict__ W2f,
              float* __restrict__ S1, float* __restrict__ S2,
              short* __restrict__ WkvT, short* __restrict__ wqT,
              short* __restrict__ W1bT, short* __restrict__ W2bT,
              short* __restrict__ W2bn, unsigned* __restrict__ barw)
{
    int i = blockIdx.x * 256 + threadIdx.x;        // 0..524287
    if (i < 257) barw[i] = 0;                      // flags[256] + go
    float w1 = m1[i], w2 = m2[i];
    W1f[i] = w1; S1[i] = 0.f;
    W2f[i] = w2; S2[i] = 0.f;
    W2bn[i] = f2b(w2);                             // natural [1024 hid][512 d]
    int n9 = i >> 9, k9 = i & 511;
    W1bT[i] = f2b(m1[(size_t)k9 * HID + n9]);
    WkvT[i] = f2b(n9 < 512 ? w_k[(size_t)k9 * D_IN + n9]
                           : w_v[(size_t)k9 * D_IN + (n9 - 512)]);
    if (i < 262144) wqT[i] = f2b(w_q[(size_t)k9 * D_IN + n9]);
    int n10 = i >> 10, k10 = i & 1023;
    W2bT[i] = f2b(m2[(size_t)k10 * D_IN + n10]);
}

// ---------------------------------------------------------------------------
// x -> bf16 copy (bit-identical to the old in-core f2b rounding).
// ---------------------------------------------------------------------------
__global__ __launch_bounds__(256)
void xb_kernel(const float* __restrict__ x, short* __restrict__ xb)
{
    int i = blockIdx.x * 256 + threadIdx.x;        // 0..1048575
    f32x4 a = ((const f32x4*)x)[i * 2];
    f32x4 b = ((const f32x4*)x)[i * 2 + 1];
    bf16x8 o;
#pragma unroll
    for (int u = 0; u < 4; ++u) { o[u] = f2b(a[u]); o[u + 4] = f2b(b[u]); }
    ((bf16x8*)xb)[i] = o;
}

// ---------------------------------------------------------------------------
// kvq: R7-PROVEN form (45.4us): grid 6144, NSLOT=3 (3 blocks/CU), n-major
// tile ids (slab m -> XCD m%8). R9's m-slab variant reverted (no gain).
// ---------------------------------------------------------------------------
__global__ __launch_bounds__(256)
void kvq_kernel(const short* __restrict__ xb, const short* __restrict__ WkvT,
                const short* __restrict__ wqT,
                short* __restrict__ KVall, short* __restrict__ Ktall,
                short* __restrict__ qall)
{
    __shared__ short KB[3 * 8192];
    const int bid = blockIdx.x;
    EPI_IDX();
    f32x4 acc[2][2];
    if (bid < 4096) {
        int t = bid >> 8, tile = bid & 255;
        int m0 = (tile & 15) * 64, n0 = (tile >> 4) * 64;
        // rows m0..m0+63 of the chunk view are contiguous in xb (64 | 256):
        const short* Akv = xb + ((size_t)(m0 >> 8) * SEQ_L + (size_t)t * CHUNK_L + (m0 & 255)) * D_IN;
        tile_gemm2<8, 3>(Akv, D_IN, WkvT, D_IN, 0, n0, KB, acc);
        short* KV = KVall + (size_t)t * ROWS * 1024;
        short* Kt = Ktall + (size_t)t * D_IN * 1024;
#pragma unroll
        for (int i = 0; i < 2; ++i)
#pragma unroll
            for (int j = 0; j < 2; ++j) {
                int m = m0 + wy_ + i * 16 + q4_, n = n0 + wxl_ + j * 16 + l16_;
                bf16x4 pk;
#pragma unroll
                for (int r = 0; r < 4; ++r) {
                    short b = f2b(acc[i][j][r]);
                    KV[(size_t)(m + r) * 1024 + n] = b;
                    pk[r] = b;
                }
                if (n < 512) *(bf16x4*)&Kt[(size_t)n * 1024 + m] = pk;
            }
    } else {
        int idx = bid - 4096;
        int m0 = (idx & 255) * 64, n0 = (idx >> 8) * 64;   // m over 16384 rows
        tile_gemm2<8, 3>(xb, D_IN, wqT, D_IN, m0, n0, KB, acc);
#pragma unroll
        for (int i = 0; i < 2; ++i)
#pragma unroll
            for (int j = 0; j < 2; ++j) {
                int m = m0 + wy_ + i * 16 + q4_, n = n0 + wxl_ + j * 16 + l16_;
#pragma unroll
                for (int r = 0; r < 4; ++r)
                    qall[(size_t)(m + r) * D_IN + n] = f2b(acc[i][j][r]);
            }
    }
}

// ---------------------------------------------------------------------------
// R17: persistent chunk loop. Grid 256 (1 block/CU, 128 KB LDS), phases
// byte-identical to the R8 h/e/dh/g21 kernels, separated by gsync (v3
// barrier). Replaces 64 launches (~9.4us each; ~5us/launch is setup/drain).
// ---------------------------------------------------------------------------
struct LoopArgs {
    short *KVall, *Ktall;
    short *W1bT, *W2bT, *W2bn;
    short *Gb, *GbT, *DG, *EVt, *DHt;
    float *W1f, *W2f, *S1, *S2;
    const float *ap, *lp, *dp;
    const int *um;
    unsigned *flags, *go;
};

__global__ __launch_bounds__(256)
void loop_kernel(LoopArgs a)
{
    __shared__ short KB[8 * 8192];
    const int bid = blockIdx.x;
    EPI_IDX();

    if (*a.um == 0) return;   // uniform: nobody arrives at any barrier

    const float alpha = sigmoid_dev(read_scalar(a.ap));
    const float lr    = sigmoid_dev(read_scalar(a.lp));
    const float decay = sigmoid_dev(read_scalar(a.dp));

    unsigned gen = 0;
    f32x4 acc[2][2];

    for (int t = 0; t < NCHUNK; ++t) {
        short* KVt = a.KVall + (size_t)t * ROWS * 1024;
        short* Ktt = a.Ktall + (size_t)t * D_IN * 1024;

        // ---- Phase H (256 tiles): h = k @ W1 -> Gb, GbT, DG ----
        {
            int m0 = (bid & 15) * 64, n0 = (bid >> 4) * 64;
            tile_gemm2<8, 8>(KVt, 1024, a.W1bT, D_IN, m0, n0, KB, acc);
#pragma unroll
            for (int i = 0; i < 2; ++i)
#pragma unroll
                for (int j = 0; j < 2; ++j) {
                    int m = m0 + wy_ + i * 16 + q4_, n = n0 + wxl_ + j * 16 + l16_;
                    bf16x4 pg;
#pragma unroll
                    for (int r = 0; r < 4; ++r) {
                        float v = acc[i][j][r];
                        float g = gelu_f(v);
                        a.Gb[(size_t)(m + r) * 1024 + n] = f2b(g);
                        a.DG[(size_t)(m + r) * 1024 + n] = f2b(dgelu_f(v));
                        pg[r] = f2b(g);
                    }
                    *(bf16x4*)&a.GbT[(size_t)n * 1024 + m] = pg;
                }
        }
        gsync(a.flags, a.go, ++gen);

        // ---- Phase E (128 tiles): e = (Gb @ W2 - v)*LS -> KVt v-half, EVt ----
        if (bid < 128) {
            int m0 = (bid & 15) * 64, n0 = (bid >> 4) * 64;
            tile_gemm2<16, 8>(a.Gb, HID, a.W2bT, HID, m0, n0, KB, acc);
#pragma unroll
            for (int i = 0; i < 2; ++i)
#pragma unroll
                for (int j = 0; j < 2; ++j) {
                    int m = m0 + wy_ + i * 16 + q4_, n = n0 + wxl_ + j * 16 + l16_;
                    bf16x4 pe;
#pragma unroll
                    for (int r = 0; r < 4; ++r) {
                        size_t ci = (size_t)(m + r) * 1024 + 512 + n;
                        float e = (acc[i][j][r] - b2f(KVt[ci])) * LOSS_SCALE;
                        KVt[ci] = f2b(e);
                        pe[r] = f2b(e);
                    }
                    *(bf16x4*)&a.EVt[(size_t)n * 1024 + m] = pe;
                }
        }
        gsync(a.flags, a.go, ++gen);

        // ---- Phase DH (256 tiles): dh = (e @ W2_old^T)*DG -> DHt ----
        {
            int m0 = (bid & 15) * 64, n0 = (bid >> 4) * 64;
            tile_gemm2<8, 8>(KVt + 512, 1024, a.W2bn, D_IN, m0, n0, KB, acc);
#pragma unroll
            for (int i = 0; i < 2; ++i)
#pragma unroll
                for (int j = 0; j < 2; ++j) {
                    int m = m0 + wy_ + i * 16 + q4_, n = n0 + wxl_ + j * 16 + l16_;
                    bf16x4 pd;
#pragma unroll
                    for (int r = 0; r < 4; ++r)
                        pd[r] = f2b(acc[i][j][r] * b2f(a.DG[(size_t)(m + r) * 1024 + n]));
                    *(bf16x4*)&a.DHt[(size_t)n * 1024 + m] = pd;
                }
        }
        gsync(a.flags, a.go, ++gen);

        // ---- Phase G: g2 (blocks 0..127) + g1 (blocks 128..255) ----
        if (bid < 128) {
            int m0 = (bid & 15) * 64, n0 = (bid >> 4) * 64;   // m=hid, n=d
            tile_gemm2<16, 8>(a.GbT, ROWS, a.EVt, ROWS, m0, n0, KB, acc);
#pragma unroll
            for (int i = 0; i < 2; ++i)
#pragma unroll
                for (int j = 0; j < 2; ++j) {
                    int m = m0 + wy_ + i * 16 + q4_, n = n0 + wxl_ + j * 16 + l16_;
                    bf16x4 pw;
#pragma unroll
                    for (int r = 0; r < 4; ++r) {
                        size_t ci = (size_t)(m + r) * D_IN + n;
                        float s = decay * a.S2[ci] - lr * acc[i][j][r];
                        a.S2[ci] = s;
                        float w = (1.0f - alpha) * a.W2f[ci] + s;
                        a.W2f[ci] = w;
                        a.W2bn[ci] = f2b(w);
                        pw[r] = f2b(w);
                    }
                    *(bf16x4*)&a.W2bT[(size_t)n * 1024 + m] = pw;
                }
        } else {
            int idx = bid - 128;
            int m0 = (idx & 7) * 64, n0 = (idx >> 3) * 64;    // m=d, n=hid
            tile_gemm2<16, 8>(Ktt, ROWS, a.DHt, ROWS, m0, n0, KB, acc);
#pragma unroll
            for (int i = 0; i < 2; ++i)
#pragma unroll
                for (int j = 0; j < 2; ++j) {
                    int m = m0 + wy_ + i * 16 + q4_, n = n0 + wxl_ + j * 16 + l16_;
                    bf16x4 pw;
#pragma unroll
                    for (int r = 0; r < 4; ++r) {
                        size_t ci = (size_t)(m + r) * HID + n;
                        float s = decay * a.S1[ci] - lr * acc[i][j][r];
                        a.S1[ci] = s;
                        float w = (1.0f - alpha) * a.W1f[ci] + s;
                        a.W1f[ci] = w;
                        pw[r] = f2b(w);
                    }
                    *(bf16x4*)&a.W1bT[(size_t)n * D_IN + m] = pw;
                }
        }
        gsync(a.flags, a.go, ++gen);
    }
}

// ---------------------------------------------------------------------------
// Readout: R8-PROVEN split form (54 + ~35us). n-major ids, NSLOT=3.
// R9's fused m-slab variant reverted (110us: occupancy 10%, FETCH 203MB).
// ---------------------------------------------------------------------------
__global__ __launch_bounds__(256)
void ro_h_kernel(const short* __restrict__ qall, const short* __restrict__ W1bT,
                 short* __restrict__ Hro)
{
    __shared__ short KB[3 * 8192];
    const int bid = blockIdx.x;
    EPI_IDX();
    int m0 = (bid & 255) * 64, n0 = (bid >> 8) * 64;   // m over 16384 rows
    f32x4 acc[2][2];
    tile_gemm2<8, 3>(qall, D_IN, W1bT, D_IN, m0, n0, KB, acc);
#pragma unroll
    for (int i = 0; i < 2; ++i)
#pragma unroll
        for (int j = 0; j < 2; ++j) {
            int m = m0 + wy_ + i * 16 + q4_, n = n0 + wxl_ + j * 16 + l16_;
#pragma unroll
            for (int r = 0; r < 4; ++r)
                Hro[(size_t)(m + r) * HID + n] = f2b(gelu_f(acc[i][j][r]));
        }
}

__global__ __launch_bounds__(256)
void ro_o_kernel(const short* __restrict__ Hro, const short* __restrict__ W2bT,
                 float* __restrict__ out)
{
    __shared__ short KB[3 * 8192];
    const int bid = blockIdx.x;
    EPI_IDX();
    int m0 = (bid & 255) * 64, n0 = (bid >> 8) * 64;  // m over 16384, n over 512
    f32x4 acc[2][2];
    tile_gemm2<16, 3>(Hro, HID, W2bT, HID, m0, n0, KB, acc);
#pragma unroll
    for (int i = 0; i < 2; ++i)
#pragma unroll
        for (int j = 0; j < 2; ++j) {
            int m = m0 + wy_ + i * 16 + q4_, n = n0 + wxl_ + j * 16 + l16_;
#pragma unroll
            for (int r = 0; r < 4; ++r)
                out[(size_t)(m + r) * D_IN + n] = acc[i][j][r];
        }
}

// ---------------------------------------------------------------------------
// Host: 6 launches (init, xb, kvq, persistent loop, ro_h, ro_o).
// ---------------------------------------------------------------------------
extern "C" void kernel_launch(void* const* d_in, const int* in_sizes, int n_in,
                              void* d_out, int out_size, void* d_ws, size_t ws_size,
                              hipStream_t stream)
{
    const float* x      = (const float*)d_in[0];
    const float* w_q    = (const float*)d_in[1];
    const float* w_k    = (const float*)d_in[2];
    const float* w_v    = (const float*)d_in[3];
    const float* mem_w1 = (const float*)d_in[4];
    const float* mem_w2 = (const float*)d_in[5];
    const float* ap     = (const float*)d_in[6];
    const float* lp     = (const float*)d_in[7];
    const float* dpp    = (const float*)d_in[8];
    const int*   um     = (const int*)d_in[9];
    float* out = (float*)d_out;

    const int nW = D_IN * HID;                 // 524288
    float* W1f = (float*)d_ws;
    float* W2f = W1f + nW;
    float* S1  = W2f + nW;
    float* S2  = S1 + nW;
    short* p   = (short*)(S2 + nW);
    short* WkvT = p;            p += nW;                    // [1024 n][512 k]
    short* wqT  = p;            p += 256 * 1024;            // [512][512]
    short* W1bT = p;            p += nW;                    // [1024 hid][512 d]
    short* W2bT = p;            p += nW;                    // [512 d][1024 hid]
    short* W2bn = p;            p += nW;                    // natural [1024 hid][512 d]
    short* Gb   = p;            p += ROWS * HID;
    short* GbT  = p;            p += ROWS * HID;
    short* DG   = p;            p += ROWS * HID;
    short* EVt  = p;            p += ROWS * D_IN;
    short* DHt  = p;            p += ROWS * HID;
    short* qall = p;            p += (size_t)NROWS_T * D_IN;        // 16 MB
    short* KVall = p;           p += (size_t)NCHUNK * ROWS * 1024;  // 32 MB
    short* Ktall = p;           p += (size_t)NCHUNK * D_IN * 1024;  // 16 MB
    short* Hro  = p;            p += (size_t)NROWS_T * HID;         // 32 MB
    short* xb   = p;            p += (size_t)NROWS_T * D_IN;        // 16 MB
    unsigned* barw = (unsigned*)p;                                  // flags[256]+go

    dim3 blk(256);
    hipLaunchKernelGGL(init_all, dim3(nW / 256), blk, 0, stream,
                       w_q, w_k, w_v, mem_w1, mem_w2,
                       W1f, W2f, S1, S2, WkvT, wqT, W1bT, W2bT, W2bn, barw);
    hipLaunchKernelGGL(xb_kernel, dim3(4096), blk, 0, stream, x, xb);
    hipLaunchKernelGGL(kvq_kernel, dim3(6144), blk, 0, stream,
                       xb, WkvT, wqT, KVall, Ktall, qall);

    LoopArgs la;
    la.KVall = KVall; la.Ktall = Ktall;
    la.W1bT = W1bT; la.W2bT = W2bT; la.W2bn = W2bn;
    la.Gb = Gb; la.GbT = GbT; la.DG = DG; la.EVt = EVt; la.DHt = DHt;
    la.W1f = W1f; la.W2f = W2f; la.S1 = S1; la.S2 = S2;
    la.ap = ap; la.lp = lp; la.dp = dpp; la.um = um;
    la.flags = barw; la.go = barw + 256;
    hipLaunchKernelGGL(loop_kernel, dim3(NB_LOOP), blk, 0, stream, la);

    hipLaunchKernelGGL(ro_h_kernel, dim3(4096), blk, 0, stream, qall, W1bT, Hro);
    hipLaunchKernelGGL(ro_o_kernel, dim3(2048), blk, 0, stream, Hro, W2bT, out);
}

// Round 11
// 718.794 us; speedup vs baseline: 2.2492x; 2.2492x over previous
//
#include <hip/hip_runtime.h>
#include <math.h>

// Problem constants
#define D_IN    512
#define HID     1024
#define CHUNK_L 256
#define NCHUNK  16
#define SEQ_L   4096
#define ROWS    1024      // 4 batches x 256 chunk rows
#define NROWS_T 16384     // total rows (4 x 4096)

typedef __attribute__((ext_vector_type(4))) float f32x4;
typedef __attribute__((ext_vector_type(8))) short bf16x8;
typedef __attribute__((ext_vector_type(4))) short bf16x4;

#define LOSS_SCALE (2.0f / 524288.0f)

__device__ __forceinline__ float gelu_f(float v) {
    return v * 0.5f * (1.0f + erff(v * 0.70710678118654752f));
}
__device__ __forceinline__ float dgelu_f(float v) {
    float cdf = 0.5f * (1.0f + erff(v * 0.70710678118654752f));
    float pdf = 0.3989422804014327f * expf(-0.5f * v * v);
    return cdf + v * pdf;
}
__device__ __forceinline__ float sigmoid_dev(float x) { return 1.0f / (1.0f + expf(-x)); }
__device__ __forceinline__ short f2b(float f) {
    unsigned u = __float_as_uint(f);
    u += 0x7fffu + ((u >> 16) & 1u);
    return (short)(u >> 16);
}
__device__ __forceinline__ float b2f(short s) {
    return __uint_as_float(((unsigned)(unsigned short)s) << 16);
}
// fp32 proven (R3); plausibility hedge kept for the 3 logits (|v| in [2.2,7])
__device__ __forceinline__ float read_scalar(const float* p) {
    float v = *p;
    if (fabsf(v) > 0.5f && fabsf(v) < 16.0f) return v;
    unsigned short lo = ((const unsigned short*)p)[0];
    return __uint_as_float(((unsigned)lo) << 16);
}

// global_load_lds width=16: wave-uniform LDS base + lane*16B dest; per-lane
// global source address (m104/m173).
__device__ __forceinline__ void glds16(const short* g, short* l) {
    __builtin_amdgcn_global_load_lds(
        (const __attribute__((address_space(1))) void*)g,
        (__attribute__((address_space(3))) void*)l, 16, 0, 0);
}

#define VMWAIT(N) asm volatile("s_waitcnt vmcnt(" #N ")" ::: "memory")

// ---------------------------------------------------------------------------
// GEMM core v2 (R5-R8-proven): 256 threads, C_tile = A[m][k] @ B[n][k]^T,
// 64x64 tile, BK=64. global_load_lds into NSLOT rolling LDS window, counted
// vmcnt depth NSLOT-1, one s_barrier per k-block, XOR granule swizzle both
// sides. Used by kvq / ro (3 blocks/CU kernels).
// ---------------------------------------------------------------------------
template<int NKB, int NSLOT>
__device__ __forceinline__ void tile_gemm2(
    const short* __restrict__ A, int lda,
    const short* __restrict__ B, int ldb,
    int m0, int n0, short* KB, f32x4 acc[2][2])
{
    const int tid = threadIdx.x;
    const int lane = tid & 63, wave = tid >> 6;
    const int wy = (wave >> 1) * 32, wx = (wave & 1) * 32;
    const int l16 = lane & 15, q = lane >> 4;

    const int ra = tid >> 3, ja = tid & 7;
    const int rb = ra + 32;
    const short* sA0 = A + (size_t)(m0 + ra) * lda + ((ja ^ (ra & 7)) << 3);
    const short* sA1 = A + (size_t)(m0 + rb) * lda + ((ja ^ (rb & 7)) << 3);
    const short* sB0 = B + (size_t)(n0 + ra) * ldb + ((ja ^ (ra & 7)) << 3);
    const short* sB1 = B + (size_t)(n0 + rb) * ldb + ((ja ^ (rb & 7)) << 3);

    f32x4 z = {0.f, 0.f, 0.f, 0.f};
    acc[0][0] = z; acc[0][1] = z; acc[1][0] = z; acc[1][1] = z;

    auto issue = [&](int kb) {
        const int ko = kb << 6;
        short* d = KB + (kb % NSLOT) * 8192 + wave * 512;
        glds16(sA0 + ko, d);
        glds16(sA1 + ko, d + 2048);
        glds16(sB0 + ko, d + 4096);
        glds16(sB1 + ko, d + 6144);
    };
#pragma unroll
    for (int kb = 0; kb < NSLOT - 1 && kb < NKB; ++kb) issue(kb);

#pragma unroll
    for (int j = 0; j < NKB; ++j) {
        int ah = NKB - 1 - j; if (ah > NSLOT - 2) ah = NSLOT - 2;
        if      (ah >= 6) VMWAIT(24);
        else if (ah == 5) VMWAIT(20);
        else if (ah == 4) VMWAIT(16);
        else if (ah == 3) VMWAIT(12);
        else if (ah == 2) VMWAIT(8);
        else if (ah == 1) VMWAIT(4);
        else              VMWAIT(0);
        __builtin_amdgcn_s_barrier();
        __builtin_amdgcn_sched_barrier(0);
        if (j + NSLOT - 1 < NKB) issue(j + NSLOT - 1);
        const short* sl = KB + (j % NSLOT) * 8192;
#pragma unroll
        for (int ks = 0; ks < 2; ++ks) {
            bf16x8 af[2], bf[2];
#pragma unroll
            for (int i = 0; i < 2; ++i) {
                int row = wy + i * 16 + l16;
                af[i] = *(const bf16x8*)&sl[(row << 6) + (((ks * 4 + q) ^ (row & 7)) << 3)];
            }
#pragma unroll
            for (int jj = 0; jj < 2; ++jj) {
                int row = wx + jj * 16 + l16;
                bf[jj] = *(const bf16x8*)&sl[4096 + (row << 6) + (((ks * 4 + q) ^ (row & 7)) << 3)];
            }
#pragma unroll
            for (int i = 0; i < 2; ++i)
#pragma unroll
                for (int jj = 0; jj < 2; ++jj)
                    acc[i][jj] = __builtin_amdgcn_mfma_f32_16x16x32_bf16(af[i], bf[jj], acc[i][jj], 0, 0, 0);
        }
    }
}

// ---------------------------------------------------------------------------
// R18 GEMM core v3: 512 threads (8 waves = 2/SIMD), same 64x64 tile & LDS
// layout as v2. Waves 0-3 accumulate k-slice ks=0, waves 4-7 ks=1 (half the
// per-wave work per iteration -> 2-wave/SIMD latency hiding). Staging split:
// threads <256 issue A (2 glds16), threads >=256 issue B — each wave's vmcnt
// gates its OWN loads; s_barrier gates the other group (non-issuers arrive
// early and wait). Final 16 KB conflict-free LDS reduction merges partials
// into grp0's acc; callers' epilogues run on tid<256 only.
// Numeric note: K-sum order differs from v2 (two half-K partials added at
// end) — bounded reorder, well within the absmax threshold.
// ---------------------------------------------------------------------------
template<int NKB, int NSLOT>
__device__ __forceinline__ void tile_gemm3(
    const short* __restrict__ A, int lda,
    const short* __restrict__ B, int ldb,
    int m0, int n0, short* KB, f32x4 acc[2][2])
{
    const int tid = threadIdx.x;           // 0..511
    const int lane = tid & 63, wave = tid >> 6;
    const int w3 = wave & 3, grp = wave >> 2;
    const int wy = (w3 >> 1) * 32, wx = (w3 & 1) * 32;
    const int l16 = lane & 15, q = lane >> 4;

    const int t2 = tid & 255;
    const int ra = t2 >> 3, ja = t2 & 7;
    const int rb = ra + 32;                // rb&7 == ra&7
    const short* s0 = (grp == 0)
        ? A + (size_t)(m0 + ra) * lda + ((ja ^ (ra & 7)) << 3)
        : B + (size_t)(n0 + ra) * ldb + ((ja ^ (ra & 7)) << 3);
    const short* s1 = (grp == 0)
        ? A + (size_t)(m0 + rb) * lda + ((ja ^ (rb & 7)) << 3)
        : B + (size_t)(n0 + rb) * ldb + ((ja ^ (rb & 7)) << 3);
    const int dbase = grp * 4096;          // A half at 0, B half at 4096

    f32x4 z = {0.f, 0.f, 0.f, 0.f};
    acc[0][0] = z; acc[0][1] = z; acc[1][0] = z; acc[1][1] = z;

    auto issue = [&](int kb) {
        const int ko = kb << 6;
        short* d = KB + (kb % NSLOT) * 8192 + dbase + w3 * 512;
        glds16(s0 + ko, d);
        glds16(s1 + ko, d + 2048);
    };
#pragma unroll
    for (int kb = 0; kb < NSLOT - 1 && kb < NKB; ++kb) issue(kb);

#pragma unroll
    for (int j = 0; j < NKB; ++j) {
        int ah = NKB - 1 - j; if (ah > NSLOT - 2) ah = NSLOT - 2;
        if      (ah >= 6) VMWAIT(12);      // 2 loads/wave/k-block
        else if (ah == 5) VMWAIT(10);
        else if (ah == 4) VMWAIT(8);
        else if (ah == 3) VMWAIT(6);
        else if (ah == 2) VMWAIT(4);
        else if (ah == 1) VMWAIT(2);
        else              VMWAIT(0);
        __builtin_amdgcn_s_barrier();
        __builtin_amdgcn_sched_barrier(0);
        if (j + NSLOT - 1 < NKB) issue(j + NSLOT - 1);
        const short* sl = KB + (j % NSLOT) * 8192;
        const int ks = grp;                // this wave's k-slice
        bf16x8 af[2], bf[2];
#pragma unroll
        for (int i = 0; i < 2; ++i) {
            int row = wy + i * 16 + l16;
            af[i] = *(const bf16x8*)&sl[(row << 6) + (((ks * 4 + q) ^ (row & 7)) << 3)];
        }
#pragma unroll
        for (int jj = 0; jj < 2; ++jj) {
            int row = wx + jj * 16 + l16;
            bf[jj] = *(const bf16x8*)&sl[4096 + (row << 6) + (((ks * 4 + q) ^ (row & 7)) << 3)];
        }
#pragma unroll
        for (int i = 0; i < 2; ++i)
#pragma unroll
            for (int jj = 0; jj < 2; ++jj)
                acc[i][jj] = __builtin_amdgcn_mfma_f32_16x16x32_bf16(af[i], bf[jj], acc[i][jj], 0, 0, 0);
    }

    // merge grp1 partials into grp0 (conflict-free: stride-256 layout)
    __syncthreads();
    float* red = (float*)KB;
    if (grp == 1) {
#pragma unroll
        for (int i = 0; i < 2; ++i)
#pragma unroll
            for (int jj = 0; jj < 2; ++jj)
#pragma unroll
                for (int r = 0; r < 4; ++r)
                    red[((i * 2 + jj) * 4 + r) * 256 + t2] = acc[i][jj][r];
    }
    __syncthreads();
    if (grp == 0) {
#pragma unroll
        for (int i = 0; i < 2; ++i)
#pragma unroll
            for (int jj = 0; jj < 2; ++jj)
#pragma unroll
                for (int r = 0; r < 4; ++r)
                    acc[i][jj][r] += red[((i * 2 + jj) * 4 + r) * 256 + t2];
    }
}

// epilogue index helper (m89 C/D layout: col=lane&15, row=(lane>>4)*4+reg)
#define EPI_IDX() \
    const int tid_ = threadIdx.x; \
    const int wy_  = (((tid_ >> 6) & 3) >> 1) * 32; \
    const int wxl_ = ((tid_ >> 6) & 1) * 32; \
    const int q4_  = ((tid_ & 63) >> 4) * 4; \
    const int l16_ = tid_ & 15;

// ---------------------------------------------------------------------------
// init: fp32 masters + bf16 operand copies (single natural W2bn)
// ---------------------------------------------------------------------------
__global__ __launch_bounds__(256)
void init_all(const float* __restrict__ w_q, const float* __restrict__ w_k,
              const float* __restrict__ w_v, const float* __restrict__ m1,
              const float* __restrict__ m2,
              float* __restrict__ W1f, float* __restrict__ W2f,
              float* __restrict__ S1, float* __restrict__ S2,
              short* __restrict__ WkvT, short* __restrict__ wqT,
              short* __restrict__ W1bT, short* __restrict__ W2bT,
              short* __restrict__ W2bn)
{
    int i = blockIdx.x * 256 + threadIdx.x;        // 0..524287
    float w1 = m1[i], w2 = m2[i];
    W1f[i] = w1; S1[i] = 0.f;
    W2f[i] = w2; S2[i] = 0.f;
    W2bn[i] = f2b(w2);                             // natural [1024 hid][512 d]
    int n9 = i >> 9, k9 = i & 511;
    W1bT[i] = f2b(m1[(size_t)k9 * HID + n9]);
    WkvT[i] = f2b(n9 < 512 ? w_k[(size_t)k9 * D_IN + n9]
                           : w_v[(size_t)k9 * D_IN + (n9 - 512)]);
    if (i < 262144) wqT[i] = f2b(w_q[(size_t)k9 * D_IN + n9]);
    int n10 = i >> 10, k10 = i & 1023;
    W2bT[i] = f2b(m2[(size_t)k10 * D_IN + n10]);
}

// ---------------------------------------------------------------------------
// x -> bf16 copy (bit-identical to the old in-core f2b rounding).
// ---------------------------------------------------------------------------
__global__ __launch_bounds__(256)
void xb_kernel(const float* __restrict__ x, short* __restrict__ xb)
{
    int i = blockIdx.x * 256 + threadIdx.x;        // 0..1048575
    f32x4 a = ((const f32x4*)x)[i * 2];
    f32x4 b = ((const f32x4*)x)[i * 2 + 1];
    bf16x8 o;
#pragma unroll
    for (int u = 0; u < 4; ++u) { o[u] = f2b(a[u]); o[u + 4] = f2b(b[u]); }
    ((bf16x8*)xb)[i] = o;
}

// ---------------------------------------------------------------------------
// kvq: R7-PROVEN (45.4us). grid 6144, 256 thr, NSLOT=3, n-major ids.
// ---------------------------------------------------------------------------
__global__ __launch_bounds__(256)
void kvq_kernel(const short* __restrict__ xb, const short* __restrict__ WkvT,
                const short* __restrict__ wqT,
                short* __restrict__ KVall, short* __restrict__ Ktall,
                short* __restrict__ qall)
{
    __shared__ short KB[3 * 8192];
    const int bid = blockIdx.x;
    EPI_IDX();
    f32x4 acc[2][2];
    if (bid < 4096) {
        int t = bid >> 8, tile = bid & 255;
        int m0 = (tile & 15) * 64, n0 = (tile >> 4) * 64;
        const short* Akv = xb + ((size_t)(m0 >> 8) * SEQ_L + (size_t)t * CHUNK_L + (m0 & 255)) * D_IN;
        tile_gemm2<8, 3>(Akv, D_IN, WkvT, D_IN, 0, n0, KB, acc);
        short* KV = KVall + (size_t)t * ROWS * 1024;
        short* Kt = Ktall + (size_t)t * D_IN * 1024;
#pragma unroll
        for (int i = 0; i < 2; ++i)
#pragma unroll
            for (int j = 0; j < 2; ++j) {
                int m = m0 + wy_ + i * 16 + q4_, n = n0 + wxl_ + j * 16 + l16_;
                bf16x4 pk;
#pragma unroll
                for (int r = 0; r < 4; ++r) {
                    short b = f2b(acc[i][j][r]);
                    KV[(size_t)(m + r) * 1024 + n] = b;
                    pk[r] = b;
                }
                if (n < 512) *(bf16x4*)&Kt[(size_t)n * 1024 + m] = pk;
            }
    } else {
        int idx = bid - 4096;
        int m0 = (idx & 255) * 64, n0 = (idx >> 8) * 64;
        tile_gemm2<8, 3>(xb, D_IN, wqT, D_IN, m0, n0, KB, acc);
#pragma unroll
        for (int i = 0; i < 2; ++i)
#pragma unroll
            for (int j = 0; j < 2; ++j) {
                int m = m0 + wy_ + i * 16 + q4_, n = n0 + wxl_ + j * 16 + l16_;
#pragma unroll
                for (int r = 0; r < 4; ++r)
                    qall[(size_t)(m + r) * D_IN + n] = f2b(acc[i][j][r]);
            }
    }
}

// ---------------------------------------------------------------------------
// R18 loop kernels: 512 threads (tile_gemm3), epilogue on tid<256.
// h = k @ W1 -> Gb, GbT, DG    grid 256
// ---------------------------------------------------------------------------
__global__ __launch_bounds__(512)
void h_kernel(const short* __restrict__ KVt, const short* __restrict__ W1bT,
              short* __restrict__ Gb, short* __restrict__ GbT, short* __restrict__ DG)
{
    __shared__ short KB[8 * 8192];
    const int bid = blockIdx.x;
    EPI_IDX();
    int m0 = (bid & 15) * 64, n0 = (bid >> 4) * 64;
    f32x4 acc[2][2];
    tile_gemm3<8, 8>(KVt, 1024, W1bT, D_IN, m0, n0, KB, acc);
    if (tid_ < 256) {
#pragma unroll
        for (int i = 0; i < 2; ++i)
#pragma unroll
            for (int j = 0; j < 2; ++j) {
                int m = m0 + wy_ + i * 16 + q4_, n = n0 + wxl_ + j * 16 + l16_;
                bf16x4 pg;
#pragma unroll
                for (int r = 0; r < 4; ++r) {
                    float v = acc[i][j][r];
                    float g = gelu_f(v);
                    Gb[(size_t)(m + r) * 1024 + n] = f2b(g);
                    DG[(size_t)(m + r) * 1024 + n] = f2b(dgelu_f(v));
                    pg[r] = f2b(g);
                }
                *(bf16x4*)&GbT[(size_t)n * 1024 + m] = pg;
            }
    }
}

// ---------------------------------------------------------------------------
// e = (Gb @ W2 - v)*LS -> KVt v-half + EVt    grid 128
// ---------------------------------------------------------------------------
__global__ __launch_bounds__(512)
void e_kernel(const short* __restrict__ Gb, const short* __restrict__ W2bT,
              short* __restrict__ KVt, short* __restrict__ EVt)
{
    __shared__ short KB[8 * 8192];
    const int bid = blockIdx.x;
    EPI_IDX();
    int m0 = (bid & 15) * 64, n0 = (bid >> 4) * 64;
    f32x4 acc[2][2];
    tile_gemm3<16, 8>(Gb, HID, W2bT, HID, m0, n0, KB, acc);
    if (tid_ < 256) {
#pragma unroll
        for (int i = 0; i < 2; ++i)
#pragma unroll
            for (int j = 0; j < 2; ++j) {
                int m = m0 + wy_ + i * 16 + q4_, n = n0 + wxl_ + j * 16 + l16_;
                bf16x4 pe;
#pragma unroll
                for (int r = 0; r < 4; ++r) {
                    size_t ci = (size_t)(m + r) * 1024 + 512 + n;
                    float e = (acc[i][j][r] - b2f(KVt[ci])) * LOSS_SCALE;
                    KVt[ci] = f2b(e);
                    pe[r] = f2b(e);
                }
                *(bf16x4*)&EVt[(size_t)n * 1024 + m] = pe;
            }
    }
}

// ---------------------------------------------------------------------------
// dh = (e @ W2_old^T)*DG -> DHt    grid 256 (reads natural W2bn)
// ---------------------------------------------------------------------------
__global__ __launch_bounds__(512)
void dh_kernel(const short* __restrict__ KVt, const short* __restrict__ W2bn,
               const short* __restrict__ DG, short* __restrict__ DHt)
{
    __shared__ short KB[8 * 8192];
    const int bid = blockIdx.x;
    EPI_IDX();
    int m0 = (bid & 15) * 64, n0 = (bid >> 4) * 64;
    f32x4 acc[2][2];
    tile_gemm3<8, 8>(KVt + 512, 1024, W2bn, D_IN, m0, n0, KB, acc);
    if (tid_ < 256) {
#pragma unroll
        for (int i = 0; i < 2; ++i)
#pragma unroll
            for (int j = 0; j < 2; ++j) {
                int m = m0 + wy_ + i * 16 + q4_, n = n0 + wxl_ + j * 16 + l16_;
                bf16x4 pd;
#pragma unroll
                for (int r = 0; r < 4; ++r)
                    pd[r] = f2b(acc[i][j][r] * b2f(DG[(size_t)(m + r) * 1024 + n]));
                *(bf16x4*)&DHt[(size_t)n * 1024 + m] = pd;
            }
    }
}

// ---------------------------------------------------------------------------
// g2 (blocks 0..127) + g1 (blocks 128..255)    grid 256
// ---------------------------------------------------------------------------
__global__ __launch_bounds__(512)
void g21_kernel(const short* __restrict__ GbT, const short* __restrict__ EVt,
                const short* __restrict__ Ktt, const short* __restrict__ DHt,
                float* __restrict__ W2f, float* __restrict__ S2,
                short* __restrict__ W2bT, short* __restrict__ W2bn,
                float* __restrict__ W1f, float* __restrict__ S1,
                short* __restrict__ W1bT,
                const float* __restrict__ ap, const float* __restrict__ lp,
                const float* __restrict__ dp, const int* __restrict__ um)
{
    __shared__ short KB[8 * 8192];
    const int bid = blockIdx.x;
    EPI_IDX();
    f32x4 acc[2][2];
    if (bid < 128) {
        int m0 = (bid & 15) * 64, n0 = (bid >> 4) * 64;   // m=hid, n=d
        tile_gemm3<16, 8>(GbT, ROWS, EVt, ROWS, m0, n0, KB, acc);
        if (tid_ < 256 && *um != 0) {
            const float alpha = sigmoid_dev(read_scalar(ap));
            const float lr    = sigmoid_dev(read_scalar(lp));
            const float decay = sigmoid_dev(read_scalar(dp));
#pragma unroll
            for (int i = 0; i < 2; ++i)
#pragma unroll
                for (int j = 0; j < 2; ++j) {
                    int m = m0 + wy_ + i * 16 + q4_, n = n0 + wxl_ + j * 16 + l16_;
                    bf16x4 pw;
#pragma unroll
                    for (int r = 0; r < 4; ++r) {
                        size_t ci = (size_t)(m + r) * D_IN + n;
                        float s = decay * S2[ci] - lr * acc[i][j][r];
                        S2[ci] = s;
                        float w = (1.0f - alpha) * W2f[ci] + s;
                        W2f[ci] = w;
                        W2bn[ci] = f2b(w);
                        pw[r] = f2b(w);
                    }
                    *(bf16x4*)&W2bT[(size_t)n * 1024 + m] = pw;
                }
        }
    } else {
        int idx = bid - 128;
        int m0 = (idx & 7) * 64, n0 = (idx >> 3) * 64;    // m=d, n=hid
        tile_gemm3<16, 8>(Ktt, ROWS, DHt, ROWS, m0, n0, KB, acc);
        if (tid_ < 256 && *um != 0) {
            const float alpha = sigmoid_dev(read_scalar(ap));
            const float lr    = sigmoid_dev(read_scalar(lp));
            const float decay = sigmoid_dev(read_scalar(dp));
#pragma unroll
            for (int i = 0; i < 2; ++i)
#pragma unroll
                for (int j = 0; j < 2; ++j) {
                    int m = m0 + wy_ + i * 16 + q4_, n = n0 + wxl_ + j * 16 + l16_;
                    bf16x4 pw;
#pragma unroll
                    for (int r = 0; r < 4; ++r) {
                        size_t ci = (size_t)(m + r) * HID + n;
                        float s = decay * S1[ci] - lr * acc[i][j][r];
                        S1[ci] = s;
                        float w = (1.0f - alpha) * W1f[ci] + s;
                        W1f[ci] = w;
                        pw[r] = f2b(w);
                    }
                    *(bf16x4*)&W1bT[(size_t)n * D_IN + m] = pw;
                }
        }
    }
}

// ---------------------------------------------------------------------------
// Readout, split, R18 mapping: XCD-chunked TIME-LOCAL ordering — a slab's
// n-tiles run consecutively on its XCD (slab stays L2-resident between its
// uses; old n-major spread them across the whole timeline -> 55MB fetch).
// xcd=bid&7, w=bid>>3: m=(w/NT)*8+xcd, n=w%NT.
// ---------------------------------------------------------------------------
__global__ __launch_bounds__(256)
void ro_h_kernel(const short* __restrict__ qall, const short* __restrict__ W1bT,
                 short* __restrict__ Hro)
{
    __shared__ short KB[3 * 8192];
    const int bid = blockIdx.x;
    EPI_IDX();
    int xcd = bid & 7, w = bid >> 3;                  // w 0..511
    int m0 = ((w >> 4) * 8 + xcd) * 64;               // slab s=w>>4 (0..31)
    int n0 = (w & 15) * 64;
    f32x4 acc[2][2];
    tile_gemm2<8, 3>(qall, D_IN, W1bT, D_IN, m0, n0, KB, acc);
#pragma unroll
    for (int i = 0; i < 2; ++i)
#pragma unroll
        for (int j = 0; j < 2; ++j) {
            int m = m0 + wy_ + i * 16 + q4_, n = n0 + wxl_ + j * 16 + l16_;
#pragma unroll
            for (int r = 0; r < 4; ++r)
                Hro[(size_t)(m + r) * HID + n] = f2b(gelu_f(acc[i][j][r]));
        }
}

__global__ __launch_bounds__(256)
void ro_o_kernel(const short* __restrict__ Hro, const short* __restrict__ W2bT,
                 float* __restrict__ out)
{
    __shared__ short KB[3 * 8192];
    const int bid = blockIdx.x;
    EPI_IDX();
    int xcd = bid & 7, w = bid >> 3;                  // w 0..255
    int m0 = ((w >> 3) * 8 + xcd) * 64;               // slab s=w>>3 (0..31)
    int n0 = (w & 7) * 64;
    f32x4 acc[2][2];
    tile_gemm2<16, 3>(Hro, HID, W2bT, HID, m0, n0, KB, acc);
#pragma unroll
    for (int i = 0; i < 2; ++i)
#pragma unroll
        for (int j = 0; j < 2; ++j) {
            int m = m0 + wy_ + i * 16 + q4_, n = n0 + wxl_ + j * 16 + l16_;
#pragma unroll
            for (int r = 0; r < 4; ++r)
                out[(size_t)(m + r) * D_IN + n] = acc[i][j][r];
        }
}

// ---------------------------------------------------------------------------
// Host: 69 launches. Loop stages per chunk: h(256x512) e(128x512)
// dh(256x512) g21(256x512). Persistence abandoned (R4/R10: agent-scope
// acquire = full per-XCD L2 invalidate per barrier -> compulsory refetch).
// ---------------------------------------------------------------------------
extern "C" void kernel_launch(void* const* d_in, const int* in_sizes, int n_in,
                              void* d_out, int out_size, void* d_ws, size_t ws_size,
                              hipStream_t stream)
{
    const float* x      = (const float*)d_in[0];
    const float* w_q    = (const float*)d_in[1];
    const float* w_k    = (const float*)d_in[2];
    const float* w_v    = (const float*)d_in[3];
    const float* mem_w1 = (const float*)d_in[4];
    const float* mem_w2 = (const float*)d_in[5];
    const float* ap     = (const float*)d_in[6];
    const float* lp     = (const float*)d_in[7];
    const float* dpp    = (const float*)d_in[8];
    const int*   um     = (const int*)d_in[9];
    float* out = (float*)d_out;

    const int nW = D_IN * HID;                 // 524288
    float* W1f = (float*)d_ws;
    float* W2f = W1f + nW;
    float* S1  = W2f + nW;
    float* S2  = S1 + nW;
    short* p   = (short*)(S2 + nW);
    short* WkvT = p;            p += nW;                    // [1024 n][512 k]
    short* wqT  = p;            p += 256 * 1024;            // [512][512]
    short* W1bT = p;            p += nW;                    // [1024 hid][512 d]
    short* W2bT = p;            p += nW;                    // [512 d][1024 hid]
    short* W2bn = p;            p += nW;                    // natural [1024 hid][512 d]
    short* Gb   = p;            p += ROWS * HID;
    short* GbT  = p;            p += ROWS * HID;
    short* DG   = p;            p += ROWS * HID;
    short* EVt  = p;            p += ROWS * D_IN;
    short* DHt  = p;            p += ROWS * HID;
    short* qall = p;            p += (size_t)NROWS_T * D_IN;        // 16 MB
    short* KVall = p;           p += (size_t)NCHUNK * ROWS * 1024;  // 32 MB
    short* Ktall = p;           p += (size_t)NCHUNK * D_IN * 1024;  // 16 MB
    short* Hro  = p;            p += (size_t)NROWS_T * HID;         // 32 MB
    short* xb   = p;            p += (size_t)NROWS_T * D_IN;        // 16 MB

    dim3 blk(256), blk2(512);
    hipLaunchKernelGGL(init_all, dim3(nW / 256), blk, 0, stream,
                       w_q, w_k, w_v, mem_w1, mem_w2,
                       W1f, W2f, S1, S2, WkvT, wqT, W1bT, W2bT, W2bn);
    hipLaunchKernelGGL(xb_kernel, dim3(4096), blk, 0, stream, x, xb);
    hipLaunchKernelGGL(kvq_kernel, dim3(6144), blk, 0, stream,
                       xb, WkvT, wqT, KVall, Ktall, qall);

    for (int t = 0; t < NCHUNK; ++t) {
        short* KVt  = KVall + (size_t)t * ROWS * 1024;
        short* Ktt  = Ktall + (size_t)t * D_IN * 1024;
        hipLaunchKernelGGL(h_kernel, dim3(256), blk2, 0, stream, KVt, W1bT, Gb, GbT, DG);
        hipLaunchKernelGGL(e_kernel, dim3(128), blk2, 0, stream, Gb, W2bT, KVt, EVt);
        hipLaunchKernelGGL(dh_kernel, dim3(256), blk2, 0, stream, KVt, W2bn, DG, DHt);
        hipLaunchKernelGGL(g21_kernel, dim3(256), blk2, 0, stream,
                           GbT, EVt, Ktt, DHt, W2f, S2, W2bT, W2bn,
                           W1f, S1, W1bT, ap, lp, dpp, um);
    }

    hipLaunchKernelGGL(ro_h_kernel, dim3(4096), blk, 0, stream, qall, W1bT, Hro);
    hipLaunchKernelGGL(ro_o_kernel, dim3(2048), blk, 0, stream, Hro, W2bT, out);
}